// Round 1
// baseline (339.949 us; speedup 1.0000x reference)
//
#include <hip/hip_runtime.h>
#include <math.h>

#define N_TOK 16384
#define DIM   2048
#define NE    64
#define TOPK  9

#define ROWS     64            // rows per block
#define DC       64            // D-chunk per K-iteration
#define NTHREADS 512
#define NWAVES   8
#define RPW      8             // rows per wave
#define NCHUNK   (DIM / DC)    // 32

__device__ __forceinline__ float wave_max64(float v) {
#pragma unroll
    for (int off = 32; off > 0; off >>= 1)
        v = fmaxf(v, __shfl_xor(v, off, 64));
    return v;
}
__device__ __forceinline__ float wave_sum64(float v) {
#pragma unroll
    for (int off = 32; off > 0; off >>= 1)
        v += __shfl_xor(v, off, 64);
    return v;
}

__global__ __launch_bounds__(NTHREADS)
void moe_router_kernel(const float* __restrict__ x,
                       const float* __restrict__ Wr,
                       const float* __restrict__ br,
                       const float* __restrict__ Wn,
                       const float* __restrict__ bn,
                       const float* __restrict__ noise_eps,
                       const float* __restrict__ gumbel,
                       float* __restrict__ out)
{
    __shared__ __align__(16) float xs [ROWS * DC];   // 16 KB  x tile [r][d]
    __shared__ __align__(16) float wrs[DC * NE];     // 16 KB  Wr chunk [d][e]
    __shared__ __align__(16) float wns[DC * NE];     // 16 KB  Wn chunk [d][e]
    __shared__ float red_imp [NWAVES * NE];          // 2 KB
    __shared__ float red_load[NWAVES * NE];          // 2 KB

    const int t    = threadIdx.x;
    const int lane = t & 63;
    const int wv   = t >> 6;
    const int row0 = blockIdx.x * ROWS;

    // ---- staging descriptors: 6 float4 per thread per chunk ----
    const int xr = t >> 4;            // 0..31
    const int xc = (t & 15) * 4;      // 0..60
    const float* gx0  = x  + (size_t)(row0 + xr)      * DIM + xc;
    const float* gx1  = x  + (size_t)(row0 + xr + 32) * DIM + xc;
    const float* gwr0 = Wr + (size_t)t * 4;
    const float* gwr1 = Wr + (size_t)(t + 512) * 4;
    const float* gwn0 = Wn + (size_t)t * 4;
    const float* gwn1 = Wn + (size_t)(t + 512) * 4;
    float* lx0  = &xs [xr * DC + xc];
    float* lx1  = &xs [(xr + 32) * DC + xc];
    float* lwr0 = &wrs[t * 4];
    float* lwr1 = &wrs[(t + 512) * 4];
    float* lwn0 = &wns[t * 4];
    float* lwn1 = &wns[(t + 512) * 4];

    float accr[RPW], accn[RPW];
#pragma unroll
    for (int r = 0; r < RPW; ++r) { accr[r] = 0.f; accn[r] = 0.f; }

    // preload chunk 0 into registers
    float4 q0 = *(const float4*)gx0;  gx0  += DC;
    float4 q1 = *(const float4*)gx1;  gx1  += DC;
    float4 q2 = *(const float4*)gwr0; gwr0 += DC * NE;
    float4 q3 = *(const float4*)gwr1; gwr1 += DC * NE;
    float4 q4 = *(const float4*)gwn0; gwn0 += DC * NE;
    float4 q5 = *(const float4*)gwn1; gwn1 += DC * NE;

    const float* xbase = &xs[wv * RPW * DC];

    for (int ch = 0; ch < NCHUNK; ++ch) {
        __syncthreads();                 // previous chunk's readers done
        *(float4*)lx0  = q0;  *(float4*)lx1  = q1;
        *(float4*)lwr0 = q2;  *(float4*)lwr1 = q3;
        *(float4*)lwn0 = q4;  *(float4*)lwn1 = q5;
        __syncthreads();
        if (ch + 1 < NCHUNK) {           // prefetch next chunk (latency hidden by compute)
            q0 = *(const float4*)gx0;  gx0  += DC;
            q1 = *(const float4*)gx1;  gx1  += DC;
            q2 = *(const float4*)gwr0; gwr0 += DC * NE;
            q3 = *(const float4*)gwr1; gwr1 += DC * NE;
            q4 = *(const float4*)gwn0; gwn0 += DC * NE;
            q5 = *(const float4*)gwn1; gwn1 += DC * NE;
        }
#pragma unroll 4
        for (int d4 = 0; d4 < DC / 4; ++d4) {
            const int db = d4 * 4;
            const float wr0 = wrs[(db + 0) * NE + lane];
            const float wr1 = wrs[(db + 1) * NE + lane];
            const float wr2 = wrs[(db + 2) * NE + lane];
            const float wr3 = wrs[(db + 3) * NE + lane];
            const float wn0 = wns[(db + 0) * NE + lane];
            const float wn1 = wns[(db + 1) * NE + lane];
            const float wn2 = wns[(db + 2) * NE + lane];
            const float wn3 = wns[(db + 3) * NE + lane];
#pragma unroll
            for (int r = 0; r < RPW; ++r) {
                const float4 xv = *(const float4*)&xbase[r * DC + db];
                accr[r] = fmaf(xv.x, wr0, accr[r]);
                accr[r] = fmaf(xv.y, wr1, accr[r]);
                accr[r] = fmaf(xv.z, wr2, accr[r]);
                accr[r] = fmaf(xv.w, wr3, accr[r]);
                accn[r] = fmaf(xv.x, wn0, accn[r]);
                accn[r] = fmaf(xv.y, wn1, accn[r]);
                accn[r] = fmaf(xv.z, wn2, accn[r]);
                accn[r] = fmaf(xv.w, wn3, accn[r]);
            }
        }
    }

    // ---------------- epilogue: per-row wave ops ----------------
    const float br_l = br[lane];
    const float bn_l = bn[lane];
    float imp_acc = 0.f, load_acc = 0.f;
    float* out_em   = out;
    float* out_rp   = out + (size_t)N_TOK * NE;
    float* out_imp  = out + (size_t)2 * N_TOK * NE;
    float* out_load = out_imp + NE;

#pragma unroll 1
    for (int r = 0; r < RPW; ++r) {
        const int row = row0 + wv * RPW + r;
        const float raw = accr[r] + br_l;
        const float nl  = accn[r] + bn_l;
        // softplus(nl) + EPS, numerically stable
        const float sd = fmaxf(nl, 0.f) + log1pf(expf(-fabsf(nl))) + 0.01f;
        const float epsv = noise_eps[(size_t)row * NE + lane];
        const float gum  = gumbel  [(size_t)row * NE + lane];
        const float noisy = fmaf(epsv, sd, raw);

        // top-9 threshold across the wave (lane = expert)
        float cur = noisy;
        float thr = 0.f, m0 = 0.f;
#pragma unroll 1
        for (int k = 0; k < TOPK; ++k) {
            const float m = wave_max64(cur);
            if (k == 0) m0 = m;
            thr = m;
            const unsigned long long b = __ballot(cur == m);
            const int first = __ffsll(b) - 1;
            if (lane == first) cur = -INFINITY;   // remove lowest-index max (jax tie order)
        }
        const float hard = (noisy >= thr) ? 1.f : 0.f;

        // mask_soft = softmax(noisy + gumbel); expert_mask = (hard - ms) + ms
        const float g  = noisy + gum;
        const float eg = expf(g - wave_max64(g));
        const float ms = eg / wave_sum64(eg);
        const float em = (hard - ms) + ms;

        // route_prob = softmax(noisy) (m0 is the wave max of noisy)
        const float en = expf(noisy - m0);
        const float rp = en / wave_sum64(en);

        // importance partial: softmax(raw)
        const float er = expf(raw - wave_max64(raw));
        imp_acc += er / wave_sum64(er);

        // load partial: 0.5*erfc(((thr - raw)/sd) * E/sqrt(2))
        const float z = (thr - raw) / sd;
        load_acc += 0.5f * erfcf(z * 45.254833995939045f);

        out_em[(size_t)row * NE + lane] = em;
        out_rp[(size_t)row * NE + lane] = rp;
    }

    red_imp [wv * NE + lane] = imp_acc;
    red_load[wv * NE + lane] = load_acc;
    __syncthreads();
    if (wv == 0) {
        float s1 = 0.f, s2 = 0.f;
#pragma unroll
        for (int i = 0; i < NWAVES; ++i) {
            s1 += red_imp [i * NE + lane];
            s2 += red_load[i * NE + lane];
        }
        atomicAdd(&out_imp [lane], s1);
        atomicAdd(&out_load[lane], s2);
    }
}

extern "C" void kernel_launch(void* const* d_in, const int* in_sizes, int n_in,
                              void* d_out, int out_size, void* d_ws, size_t ws_size,
                              hipStream_t stream)
{
    const float* x         = (const float*)d_in[0];
    const float* Wr        = (const float*)d_in[1];
    const float* br        = (const float*)d_in[2];
    const float* Wn        = (const float*)d_in[3];
    const float* bn        = (const float*)d_in[4];
    const float* noise_eps = (const float*)d_in[5];
    const float* gumbel    = (const float*)d_in[6];
    float* out = (float*)d_out;

    // importance/load are atomically accumulated — zero them (d_out is poisoned 0xAA)
    hipMemsetAsync((char*)d_out + (size_t)2 * N_TOK * NE * sizeof(float), 0,
                   2 * NE * sizeof(float), stream);

    moe_router_kernel<<<N_TOK / ROWS, NTHREADS, 0, stream>>>(
        x, Wr, br, Wn, bn, noise_eps, gumbel, out);
}